// Round 8
// baseline (438.827 us; speedup 1.0000x reference)
//
#include <hip/hip_runtime.h>

#define B_TOT 4096
#define T_LEN 512
#define DIN   8
#define H_DIM 50

typedef __attribute__((ext_vector_type(8))) short  short8;   // 8 bf16
typedef __attribute__((ext_vector_type(4))) float  floatx4;  // MFMA acc

__device__ __forceinline__ ushort f2bf_rne(float f) {
  uint u = __float_as_uint(f);
  u += 0x7FFFu + ((u >> 16) & 1u);
  return (ushort)(u >> 16);
}
__device__ __forceinline__ ushort f2bf_trunc(float f) {
  return (ushort)(__float_as_uint(f) >> 16);
}
__device__ __forceinline__ float bf2f(ushort b) {
  return __uint_as_float(((uint)b) << 16);
}
__device__ __forceinline__ float fast_tanh(float v) {
  // tanh(v) = 1 - 2/(1+e^{2v}); abs err ~1e-7
  float e = __expf(2.0f * v);
  return 1.0f - 2.0f * __builtin_amdgcn_rcpf(1.0f + e);
}

// pack v -> same-order [hi,lo] and swapped [lo,hi] bf16 pair regs.
// Same numerics as R6: rne hi, trunc lo of residual.
__device__ __forceinline__ void packHL(float v, uint& rs, uint& rw) {
  uint u  = __float_as_uint(v);
  uint hi = (u + (0x7FFFu + ((u >> 16) & 1u))) >> 16;   // rne hi (16b)
  uint hb = hi << 16;                                    // bf2f(hi) bits
  float resid = v - __uint_as_float(hb);
  uint lo = __float_as_uint(resid) >> 16;                // trunc lo (16b)
  rs = hi | (lo << 16);   // slot even = hi, slot odd = lo
  rw = lo | hb;           // slot even = lo, slot odd = hi
}

// ---------------------------------------------------------------------------
// Register-resident recurrence, zero LDS, zero barriers, one wave per CU.
//
// MFMA roles swapped vs R0-R7: first operand = W (m = output dim i),
// second = h (n = batch). Then C layout (row i = kg*4+r, col = batch) is
// EXACTLY the per-lane layout the next step's h-operand fragment needs
// (frag kfrag: k = kfrag*16 + kg*4 + j/2, n = col): C-tile mt feeds B-frag
// kfrag=mt lane-locally. The serial loop is MFMA -> tanh -> bitpack -> MFMA
// entirely in VGPRs. Fragment index formulas are carried over verbatim from
// the harness-verified R6 kernel (k' = f*32 + kg*8 + j, value p = k'/2,
// even slot = hi, odd = lo; dual-order product = exact (hiW+loW)(hiH+loH)).
//
// k space: 0..49 = h, 50..57 = x_t, 58..63 = zero pad.
// Frag 3 per lane (k = 48+kg*4+p): kg0: [h48,h49,x0,x1]; kg1: [x2..x5];
// kg2: [x6,x7,0,0]; kg3: zeros. x loads are per-lane float2 pairs with a
// depth-3 register prefetch queue.
// ---------------------------------------------------------------------------
__global__ __launch_bounds__(64, 1) void rnn_fused(
    const float* __restrict__ x, const float* __restrict__ W_ih,
    const float* __restrict__ W_hh, const float* __restrict__ b_ih,
    const float* __restrict__ b_hh, const float* __restrict__ fc_W,
    const float* __restrict__ fc_b, float* __restrict__ out)
{
  const int lane = threadIdx.x;    // one wave
  const int col  = lane & 15;      // n sub-index: batch (and A-frag m row)
  const int kg   = lane >> 4;      // 0..3 k-group
  const int b0   = blockIdx.x * 16;

  union FU { uint u[4]; short8 v; };

  // ---- W as first-operand frags (interleaved hi/lo), VGPR-resident --------
  short8 Aw[4][4];                 // [m-tile][kfrag]
#pragma unroll
  for (int mt = 0; mt < 4; ++mt) {
    const int i = mt * 16 + col;   // output dim this lane's A-row
    const bool ilive = (i < H_DIM);
#pragma unroll
    for (int f = 0; f < 4; ++f) {
      FU a;
#pragma unroll
      for (int j2 = 0; j2 < 4; ++j2) {
        const int p = f * 16 + kg * 4 + j2;   // value index 0..63
        float w = 0.f;
        if (ilive) {
          if (p < H_DIM)            w = W_hh[i * H_DIM + p];
          else if (p < H_DIM + DIN) w = W_ih[i * DIN + (p - H_DIM)];
        }
        ushort hi = f2bf_rne(w);
        ushort lo = f2bf_trunc(w - bf2f(hi));
        a.u[j2] = (uint)hi | ((uint)lo << 16);   // even slot hi, odd lo
      }
      Aw[mt][f] = a.v;
    }
  }
  // bias per C row i = mt*16 + kg*4 + r
  floatx4 biasv[4];
#pragma unroll
  for (int mt = 0; mt < 4; ++mt)
#pragma unroll
    for (int r = 0; r < 4; ++r) {
      const int i = mt * 16 + kg * 4 + r;
      biasv[mt][r] = (i < H_DIM) ? (b_ih[i] + b_hh[i]) : 0.f;
    }

  // ---- x per-lane float2 pairs + depth-3 prefetch queue --------------------
  const int dA = (kg == 0) ? 0 : (kg == 1) ? 2 : (kg == 2) ? 6 : 0;
  const int dB = (kg == 1) ? 4 : dA;
  const float* xrow = x + (size_t)(b0 + col) * T_LEN * DIN;
  float2 qA0 = *(const float2*)(xrow + 0 * DIN + dA);
  float2 qB0 = *(const float2*)(xrow + 0 * DIN + dB);
  float2 qA1 = *(const float2*)(xrow + 1 * DIN + dA);
  float2 qB1 = *(const float2*)(xrow + 1 * DIN + dB);
  float2 qA2 = *(const float2*)(xrow + 2 * DIN + dA);
  float2 qB2 = *(const float2*)(xrow + 2 * DIN + dB);

  // ---- h state: th[mt][r] = h[i = mt*16+kg*4+r][batch=col], h_0 = 0 --------
  float th[4][4];
#pragma unroll
  for (int mt = 0; mt < 4; ++mt)
#pragma unroll
    for (int r = 0; r < 4; ++r) th[mt][r] = 0.f;

  for (int t = 0; t < T_LEN; ++t) {
    // ---- build h-operand frags (dual order), lane-local from th -----------
    FU bs[4], bw[4];
#pragma unroll
    for (int f = 0; f < 3; ++f)
#pragma unroll
      for (int p = 0; p < 4; ++p)
        packHL(th[f][p], bs[f].u[p], bw[f].u[p]);

    float v3_0, v3_1, v3_2, v3_3;
    if (kg == 0)      { v3_0 = th[3][0]; v3_1 = th[3][1]; v3_2 = qA0.x; v3_3 = qA0.y; }
    else if (kg == 1) { v3_0 = qA0.x;    v3_1 = qA0.y;    v3_2 = qB0.x; v3_3 = qB0.y; }
    else if (kg == 2) { v3_0 = qA0.x;    v3_1 = qA0.y;    v3_2 = 0.f;   v3_3 = 0.f; }
    else              { v3_0 = 0.f;      v3_1 = 0.f;      v3_2 = 0.f;   v3_3 = 0.f; }
    packHL(v3_0, bs[3].u[0], bw[3].u[0]);
    packHL(v3_1, bs[3].u[1], bw[3].u[1]);
    packHL(v3_2, bs[3].u[2], bw[3].u[2]);
    packHL(v3_3, bs[3].u[3], bw[3].u[3]);

    // rotate prefetch queue, issue load for t+3
    qA0 = qA1; qB0 = qB1; qA1 = qA2; qB1 = qB2;
    {
      int tn = t + 3; if (tn > T_LEN - 1) tn = T_LEN - 1;
      qA2 = *(const float2*)(xrow + (size_t)tn * DIN + dA);
      qB2 = *(const float2*)(xrow + (size_t)tn * DIN + dB);
    }

    // ---- MFMA: 4 m-tiles x (4 kfrags x 2 orders) = 32 ---------------------
#pragma unroll
    for (int mt = 0; mt < 4; ++mt) {
      floatx4 aS = biasv[mt];
      aS = __builtin_amdgcn_mfma_f32_16x16x32_bf16(Aw[mt][0], bs[0].v, aS, 0, 0, 0);
      aS = __builtin_amdgcn_mfma_f32_16x16x32_bf16(Aw[mt][1], bs[1].v, aS, 0, 0, 0);
      aS = __builtin_amdgcn_mfma_f32_16x16x32_bf16(Aw[mt][2], bs[2].v, aS, 0, 0, 0);
      aS = __builtin_amdgcn_mfma_f32_16x16x32_bf16(Aw[mt][3], bs[3].v, aS, 0, 0, 0);
      floatx4 aW = {0.f, 0.f, 0.f, 0.f};
      aW = __builtin_amdgcn_mfma_f32_16x16x32_bf16(Aw[mt][0], bw[0].v, aW, 0, 0, 0);
      aW = __builtin_amdgcn_mfma_f32_16x16x32_bf16(Aw[mt][1], bw[1].v, aW, 0, 0, 0);
      aW = __builtin_amdgcn_mfma_f32_16x16x32_bf16(Aw[mt][2], bw[2].v, aW, 0, 0, 0);
      aW = __builtin_amdgcn_mfma_f32_16x16x32_bf16(Aw[mt][3], bw[3].v, aW, 0, 0, 0);
      floatx4 s = aS + aW;
      th[mt][0] = fast_tanh(s[0]);
      th[mt][1] = fast_tanh(s[1]);
      if (mt < 3) {                 // m-tile 3 rows 50..63 dead beyond i=48,49
        th[mt][2] = fast_tanh(s[2]);
        th[mt][3] = fast_tanh(s[3]);
      }
    }
  }

  // ---- fc readout: per-lane partial over its output dims, reduce over kg --
  float p = 0.f;
#pragma unroll
  for (int mt = 0; mt < 3; ++mt)
#pragma unroll
    for (int r = 0; r < 4; ++r)
      p += th[mt][r] * fc_W[mt * 16 + kg * 4 + r];
  if (kg == 0) p += th[3][0] * fc_W[48] + th[3][1] * fc_W[49];
  p += __shfl_xor(p, 16);
  p += __shfl_xor(p, 32);
  if (kg == 0) out[b0 + col] = p + fc_b[0];
}

extern "C" void kernel_launch(void* const* d_in, const int* in_sizes, int n_in,
                              void* d_out, int out_size, void* d_ws, size_t ws_size,
                              hipStream_t stream) {
  const float* x    = (const float*)d_in[0];
  const float* W_ih = (const float*)d_in[1];
  const float* W_hh = (const float*)d_in[2];
  const float* b_ih = (const float*)d_in[3];
  const float* b_hh = (const float*)d_in[4];
  const float* fc_W = (const float*)d_in[5];
  const float* fc_b = (const float*)d_in[6];
  rnn_fused<<<dim3(B_TOT / 16), dim3(64), 0, stream>>>(
      x, W_ih, W_hh, b_ih, b_hh, fc_W, fc_b, (float*)d_out);
}